// Round 1
// baseline (628.178 us; speedup 1.0000x reference)
//
#include <hip/hip_runtime.h>
#include <hip/hip_bf16.h>

#define B_  64
#define T_  1000
#define F_  140
#define D_  256
#define EPS_ 1e-5f

// ---------------- K0: transpose lin_w (D,D) -> lwT (d-major) for coalesced gathers
__global__ __launch_bounds__(256) void k0_transpose(const float* __restrict__ lw,
                                                    float* __restrict__ lwT) {
  int i = blockIdx.x * 256 + threadIdx.x;   // i over D*D
  int e = i >> 8, d = i & 255;
  lwT[(size_t)d * D_ + e] = lw[(size_t)e * D_ + d];
}

// ---------------- K1: pointwise GEMM  h[t,b,d] = sum_f x[b,t,f]*pw_w[d,f] + pw_b[d]
// fp32 VALU, 64x64 tile, 256 threads, 4x4 per thread. Output bf16 in (T,B,D).
__global__ __launch_bounds__(256) void k1_pw_gemm(const float* __restrict__ x,
                                                  const float* __restrict__ w,
                                                  const float* __restrict__ bias,
                                                  __hip_bfloat16* __restrict__ h) {
  __shared__ float As[16][64];
  __shared__ float Bs[16][64];
  const int m0 = blockIdx.x * 64;           // over M = B*T = 64000
  const int n0 = blockIdx.y * 64;           // over D
  const int tid = threadIdx.x;
  const int tx = tid & 15, ty = tid >> 4;
  const int row = tid & 63, kg = tid >> 6;
  float acc[4][4] = {};
  for (int k0 = 0; k0 < F_; k0 += 16) {
    const int kb = k0 + kg * 4;
    float4 av = make_float4(0.f, 0.f, 0.f, 0.f);
    float4 bv = make_float4(0.f, 0.f, 0.f, 0.f);
    if (kb < F_) {   // F=140 divisible by 4, so kb<140 implies full float4 in-bounds
      av = *(const float4*)(x + (size_t)(m0 + row) * F_ + kb);
      bv = *(const float4*)(w + (size_t)(n0 + row) * F_ + kb);
    }
    __syncthreads();
    As[kg * 4 + 0][row] = av.x; As[kg * 4 + 1][row] = av.y;
    As[kg * 4 + 2][row] = av.z; As[kg * 4 + 3][row] = av.w;
    Bs[kg * 4 + 0][row] = bv.x; Bs[kg * 4 + 1][row] = bv.y;
    Bs[kg * 4 + 2][row] = bv.z; Bs[kg * 4 + 3][row] = bv.w;
    __syncthreads();
#pragma unroll
    for (int kk = 0; kk < 16; kk++) {
      float4 a4 = *(const float4*)&As[kk][ty * 4];
      float4 b4 = *(const float4*)&Bs[kk][tx * 4];
      float a[4] = {a4.x, a4.y, a4.z, a4.w};
      float b[4] = {b4.x, b4.y, b4.z, b4.w};
#pragma unroll
      for (int i = 0; i < 4; i++)
#pragma unroll
        for (int j = 0; j < 4; j++) acc[i][j] += a[i] * b[j];
    }
  }
  // epilogue: add bias, convert bf16, scatter rows to (t,b,d)
#pragma unroll
  for (int i = 0; i < 4; i++) {
    int m = m0 + ty * 4 + i;
    int bb = m / T_;
    int t = m - bb * T_;
    size_t off = ((size_t)t * B_ + bb) * D_ + n0 + tx * 4;
    __hip_bfloat16 tmp[4];
#pragma unroll
    for (int j = 0; j < 4; j++)
      tmp[j] = __float2bfloat16(acc[i][j] + bias[n0 + tx * 4 + j]);
    *(ushort4*)(h + off) = *(ushort4*)tmp;
  }
}

// ---------------- K2: depthwise conv (K=7, same pad, cross-correlation) + BN1 + LIF1
// one thread per (b,d); spikes packed to bitmasks via ballot. bits layout: [(b*T + t)*4 + dq]
__global__ __launch_bounds__(64) void k2_dw_lif(const __hip_bfloat16* __restrict__ h,
                                                const float* __restrict__ dww,
                                                const float* __restrict__ g1,
                                                const float* __restrict__ b1,
                                                const float* __restrict__ m1,
                                                const float* __restrict__ v1,
                                                unsigned long long* __restrict__ bits) {
  const int b = blockIdx.x >> 2;
  const int dq = blockIdx.x & 3;
  const int d = dq * 64 + threadIdx.x;
  float w[7];
#pragma unroll
  for (int k = 0; k < 7; k++) w[k] = dww[d * 7 + k];
  const float sc = g1[d] * rsqrtf(v1[d] + EPS_);
  const float sh = b1[d] - m1[d] * sc;
  const __hip_bfloat16* hp = h + (size_t)b * D_ + d;
  const size_t ts = (size_t)B_ * D_;     // t-stride in h

  float win0 = 0.f, win1 = 0.f, win2 = 0.f;                 // h[t-3..t-1]
  float win3 = __bfloat162float(hp[0 * ts]);                // h[t]
  float win4 = __bfloat162float(hp[1 * ts]);
  float win5 = __bfloat162float(hp[2 * ts]);
  float v = 0.f;

  const int U = 32;   // chunk; double-buffered prefetch to hide HBM latency (1 wave/CU)
  float cur[U], nxt[U];
#pragma unroll
  for (int i = 0; i < U; i++) {   // cur holds h[t0+3 .. t0+3+U-1] for t0=0
    int tt = 3 + i;
    cur[i] = (tt < T_) ? __bfloat162float(hp[(size_t)tt * ts]) : 0.f;
  }
  for (int t0 = 0; t0 < T_; t0 += U) {
#pragma unroll
    for (int i = 0; i < U; i++) {   // prefetch next chunk's inputs
      int tt = t0 + U + 3 + i;
      nxt[i] = (tt < T_) ? __bfloat162float(hp[(size_t)tt * ts]) : 0.f;
    }
#pragma unroll
    for (int i = 0; i < U; i++) {
      float conv = win0 * w[0] + win1 * w[1] + win2 * w[2] + win3 * w[3] +
                   win4 * w[4] + win5 * w[5] + cur[i] * w[6];
      float u = conv * sc + sh;
      v = 0.5f * (v + u);                 // v += (u - v)/tau, tau = 2
      bool s = (v >= 1.0f);               // spike(v - V_TH)
      unsigned long long mask = __ballot(s);
      if (threadIdx.x == 0)
        bits[((size_t)b * T_ + (t0 + i)) * 4 + dq] = mask;
      v = s ? 0.f : v;                    // hard reset
      win0 = win1; win1 = win2; win2 = win3; win3 = win4; win4 = win5; win5 = cur[i];
    }
#pragma unroll
    for (int i = 0; i < U; i++) cur[i] = nxt[i];
  }
}

// ---------------- K3: sparse linear (spikes @ lin_w^T) + BN2 + LIF2 + residual
// block = (b, e-chunk of 64). All of b's spike bitmasks staged in LDS (32 KB).
__global__ __launch_bounds__(64) void k3_lin_lif(const unsigned long long* __restrict__ bits,
                                                 const float* __restrict__ lwT,
                                                 const float* __restrict__ g2,
                                                 const float* __restrict__ b2,
                                                 const float* __restrict__ m2,
                                                 const float* __restrict__ v2,
                                                 float* __restrict__ out) {
  __shared__ unsigned long long sb[T_ * 4];
  const int b = blockIdx.x >> 2;
  const int eq = blockIdx.x & 3;
  const int e = eq * 64 + threadIdx.x;
  const unsigned long long* bp = bits + (size_t)b * T_ * 4;
  for (int i = threadIdx.x; i < T_ * 4; i += 64) sb[i] = bp[i];
  __syncthreads();

  const float sc = g2[e] * rsqrtf(v2[e] + EPS_);
  const float sh = b2[e] - m2[e] * sc;
  float v = 0.f;
  float* op = out + (size_t)b * D_ + e;
  const size_t ts = (size_t)B_ * D_;

  for (int t = 0; t < T_; t++) {
    unsigned long long w0 = sb[t * 4 + 0], w1 = sb[t * 4 + 1];
    unsigned long long w2 = sb[t * 4 + 2], w3 = sb[t * 4 + 3];
    float acc = 0.f;
    if (w0 | w1 | w2 | w3) {   // wave-uniform: sparse gather only when spikes present
      unsigned long long mm;
      mm = w0; while (mm) { int l = __builtin_ctzll(mm); mm &= mm - 1; acc += lwT[(size_t)(l) * D_ + e]; }
      mm = w1; while (mm) { int l = __builtin_ctzll(mm); mm &= mm - 1; acc += lwT[(size_t)(64 + l) * D_ + e]; }
      mm = w2; while (mm) { int l = __builtin_ctzll(mm); mm &= mm - 1; acc += lwT[(size_t)(128 + l) * D_ + e]; }
      mm = w3; while (mm) { int l = __builtin_ctzll(mm); mm &= mm - 1; acc += lwT[(size_t)(192 + l) * D_ + e]; }
    }
    float u = acc * sc + sh;          // BN2 (eval): u*g*rsqrt(var+eps) + (b - m*scale)
    v = 0.5f * (v + u);
    bool s = (v >= 1.0f);
    unsigned long long myw = sb[t * 4 + eq];
    float s1 = (float)((myw >> threadIdx.x) & 1ull);   // residual spike
    op[(size_t)t * ts] = (s ? 1.0f : 0.0f) + s1;
    v = s ? 0.f : v;
  }
}

extern "C" void kernel_launch(void* const* d_in, const int* in_sizes, int n_in,
                              void* d_out, int out_size, void* d_ws, size_t ws_size,
                              hipStream_t stream) {
  const float* x    = (const float*)d_in[0];
  const float* pw_w = (const float*)d_in[1];
  const float* pw_b = (const float*)d_in[2];
  const float* dw_w = (const float*)d_in[3];
  const float* g1   = (const float*)d_in[4];
  const float* b1   = (const float*)d_in[5];
  const float* m1   = (const float*)d_in[6];
  const float* v1   = (const float*)d_in[7];
  const float* lw   = (const float*)d_in[8];
  const float* g2   = (const float*)d_in[9];
  const float* b2   = (const float*)d_in[10];
  const float* m2   = (const float*)d_in[11];
  const float* v2   = (const float*)d_in[12];
  float* out = (float*)d_out;

  char* ws = (char*)d_ws;
  __hip_bfloat16* h = (__hip_bfloat16*)ws;                              // 32,768,000 B
  unsigned long long* bits = (unsigned long long*)(ws + 32768000);      //  2,048,000 B
  float* lwT = (float*)(ws + 32768000 + 2048000);                       //    262,144 B

  k0_transpose<<<(D_ * D_) / 256, 256, 0, stream>>>(lw, lwT);
  dim3 g_gemm((B_ * T_) / 64, D_ / 64);
  k1_pw_gemm<<<g_gemm, 256, 0, stream>>>(x, pw_w, pw_b, h);
  k2_dw_lif<<<B_ * 4, 64, 0, stream>>>(h, dw_w, g1, b1, m1, v1, bits);
  k3_lin_lif<<<B_ * 4, 64, 0, stream>>>(bits, lwT, g2, b2, m2, v2, out);
}

// Round 2
// 233.680 us; speedup vs baseline: 2.6882x; 2.6882x over previous
//
#include <hip/hip_runtime.h>
#include <hip/hip_bf16.h>

#define B_  64
#define T_  1000
#define F_  140
#define D_  256
#define EPS_ 1e-5f

// time-chunked scan parameters: v-influence decays 2^-step (tau=2), so W=24
// warmup steps from v=0 reproduce the true state to <6e-8 before any chunk.
#define CL_ 50     // steps written per chunk
#define NC_ 20     // chunks (CL_*NC_ == T_)
#define W_  24     // warmup steps

// ---------------- K0: transpose lin_w (D,D) -> lwT (d-major) for coalesced gathers
__global__ __launch_bounds__(256) void k0_transpose(const float* __restrict__ lw,
                                                    float* __restrict__ lwT) {
  int i = blockIdx.x * 256 + threadIdx.x;   // i over D*D
  int e = i >> 8, d = i & 255;
  lwT[(size_t)d * D_ + e] = lw[(size_t)e * D_ + d];
}

// ---------------- K1: pointwise GEMM  h[t,b,d] = sum_f x[b,t,f]*pw_w[d,f] + pw_b[d]
// fp32 VALU, 64x64 tile, 256 threads, 4x4 per thread. Output bf16 in (T,B,D).
__global__ __launch_bounds__(256) void k1_pw_gemm(const float* __restrict__ x,
                                                  const float* __restrict__ w,
                                                  const float* __restrict__ bias,
                                                  __hip_bfloat16* __restrict__ h) {
  __shared__ float As[16][64];
  __shared__ float Bs[16][64];
  const int m0 = blockIdx.x * 64;           // over M = B*T = 64000
  const int n0 = blockIdx.y * 64;           // over D
  const int tid = threadIdx.x;
  const int tx = tid & 15, ty = tid >> 4;
  const int row = tid & 63, kg = tid >> 6;
  float acc[4][4] = {};
  for (int k0 = 0; k0 < F_; k0 += 16) {
    const int kb = k0 + kg * 4;
    float4 av = make_float4(0.f, 0.f, 0.f, 0.f);
    float4 bv = make_float4(0.f, 0.f, 0.f, 0.f);
    if (kb < F_) {   // F=140 divisible by 4, so kb<140 implies full float4 in-bounds
      av = *(const float4*)(x + (size_t)(m0 + row) * F_ + kb);
      bv = *(const float4*)(w + (size_t)(n0 + row) * F_ + kb);
    }
    __syncthreads();
    As[kg * 4 + 0][row] = av.x; As[kg * 4 + 1][row] = av.y;
    As[kg * 4 + 2][row] = av.z; As[kg * 4 + 3][row] = av.w;
    Bs[kg * 4 + 0][row] = bv.x; Bs[kg * 4 + 1][row] = bv.y;
    Bs[kg * 4 + 2][row] = bv.z; Bs[kg * 4 + 3][row] = bv.w;
    __syncthreads();
#pragma unroll
    for (int kk = 0; kk < 16; kk++) {
      float4 a4 = *(const float4*)&As[kk][ty * 4];
      float4 b4 = *(const float4*)&Bs[kk][tx * 4];
      float a[4] = {a4.x, a4.y, a4.z, a4.w};
      float b[4] = {b4.x, b4.y, b4.z, b4.w};
#pragma unroll
      for (int i = 0; i < 4; i++)
#pragma unroll
        for (int j = 0; j < 4; j++) acc[i][j] += a[i] * b[j];
    }
  }
#pragma unroll
  for (int i = 0; i < 4; i++) {
    int m = m0 + ty * 4 + i;
    int bb = m / T_;
    int t = m - bb * T_;
    size_t off = ((size_t)t * B_ + bb) * D_ + n0 + tx * 4;
    __hip_bfloat16 tmp[4];
#pragma unroll
    for (int j = 0; j < 4; j++)
      tmp[j] = __float2bfloat16(acc[i][j] + bias[n0 + tx * 4 + j]);
    *(ushort4*)(h + off) = *(ushort4*)tmp;
  }
}

// ---------------- K2: depthwise conv (K=7, same pad) + BN1 + LIF1, time-chunked
// grid.x = b*4+dq (256), grid.y = time chunk (NC_). One thread per (b,d).
// Spikes packed to bitmasks via ballot. bits layout: [(b*T + t)*4 + dq]
__global__ void k2_dw_lif(const __hip_bfloat16* __restrict__ h,
                          const float* __restrict__ dww,
                          const float* __restrict__ g1,
                          const float* __restrict__ b1,
                          const float* __restrict__ m1,
                          const float* __restrict__ v1,
                          unsigned long long* __restrict__ bits) {
  const int b = blockIdx.x >> 2;
  const int dq = blockIdx.x & 3;
  const int d = dq * 64 + threadIdx.x;
  const int t0 = blockIdx.y * CL_;
  const int tstart = (t0 - W_ > 0) ? t0 - W_ : 0;
  const int tend = t0 + CL_;          // <= T_
  const int nsteps = tend - tstart;   // <= CL_ + W_ = 74

  float w[7];
#pragma unroll
  for (int k = 0; k < 7; k++) w[k] = dww[d * 7 + k];
  const float sc = g1[d] * rsqrtf(v1[d] + EPS_);
  const float sh = b1[d] - m1[d] * sc;
  const __hip_bfloat16* hp = h + (size_t)b * D_ + d;
  const size_t ts = (size_t)B_ * D_;     // t-stride in h

  // window regs: win0..win5 = h[t-3 .. t+2] at t = tstart
  float win0 = (tstart - 3 >= 0) ? __bfloat162float(hp[(size_t)(tstart - 3) * ts]) : 0.f;
  float win1 = (tstart - 2 >= 0) ? __bfloat162float(hp[(size_t)(tstart - 2) * ts]) : 0.f;
  float win2 = (tstart - 1 >= 0) ? __bfloat162float(hp[(size_t)(tstart - 1) * ts]) : 0.f;
  float win3 = __bfloat162float(hp[(size_t)(tstart + 0) * ts]);
  float win4 = __bfloat162float(hp[(size_t)(tstart + 1) * ts]);
  float win5 = __bfloat162float(hp[(size_t)(tstart + 2) * ts]);
  float v = 0.f;

  const int U = 8;     // prefetch queue depth (small: no VGPR spill)
  float buf[U], nbuf[U];
#pragma unroll
  for (int i = 0; i < U; i++) {   // buf[i] = h[tstart+3+i]
    int tt = tstart + 3 + i;
    buf[i] = (tt < T_) ? __bfloat162float(hp[(size_t)tt * ts]) : 0.f;
  }
  for (int s0 = 0; s0 < nsteps; s0 += U) {
#pragma unroll
    for (int i = 0; i < U; i++) {   // prefetch next sub-chunk
      int tt = tstart + 3 + s0 + U + i;
      nbuf[i] = (tt < T_) ? __bfloat162float(hp[(size_t)tt * ts]) : 0.f;
    }
#pragma unroll
    for (int i = 0; i < U; i++) {
      if (s0 + i >= nsteps) break;         // wave-uniform
      const int t = tstart + s0 + i;
      float conv = win0 * w[0] + win1 * w[1] + win2 * w[2] + win3 * w[3] +
                   win4 * w[4] + win5 * w[5] + buf[i] * w[6];
      float u = conv * sc + sh;
      v = 0.5f * (v + u);                  // v += (u - v)/tau, tau = 2
      bool s = (v >= 1.0f);                // spike(v - V_TH)
      unsigned long long mask = __ballot(s);
      if (t >= t0 && threadIdx.x == 0)
        bits[((size_t)b * T_ + t) * 4 + dq] = mask;
      v = s ? 0.f : v;                     // hard reset
      win0 = win1; win1 = win2; win2 = win3; win3 = win4; win4 = win5; win5 = buf[i];
    }
#pragma unroll
    for (int i = 0; i < U; i++) buf[i] = nbuf[i];
  }
}

// ---------------- K3: sparse linear (spikes @ lin_w^T) + BN2 + LIF2 + residual
// grid.x = b*4+eq (256), grid.y = time chunk. Window bitmasks staged in LDS.
__global__ void k3_lin_lif(const unsigned long long* __restrict__ bits,
                           const float* __restrict__ lwT,
                           const float* __restrict__ g2,
                           const float* __restrict__ b2,
                           const float* __restrict__ m2,
                           const float* __restrict__ v2,
                           float* __restrict__ out) {
  __shared__ unsigned long long sb[(CL_ + W_) * 4];
  const int b = blockIdx.x >> 2;
  const int eq = blockIdx.x & 3;
  const int e = eq * 64 + threadIdx.x;
  const int t0 = blockIdx.y * CL_;
  const int tstart = (t0 - W_ > 0) ? t0 - W_ : 0;
  const int tend = t0 + CL_;
  const int nw = (tend - tstart) * 4;
  const unsigned long long* bp = bits + ((size_t)b * T_ + tstart) * 4;
  for (int i = threadIdx.x; i < nw; i += 64) sb[i] = bp[i];
  __syncthreads();

  const float sc = g2[e] * rsqrtf(v2[e] + EPS_);
  const float sh = b2[e] - m2[e] * sc;
  float v = 0.f;
  float* op = out + (size_t)b * D_ + e;
  const size_t ts = (size_t)B_ * D_;

  for (int t = tstart; t < tend; t++) {
    const int idx = (t - tstart) * 4;
    unsigned long long w0 = sb[idx + 0], w1 = sb[idx + 1];
    unsigned long long w2 = sb[idx + 2], w3 = sb[idx + 3];
    float acc = 0.f;
    if (w0 | w1 | w2 | w3) {   // wave-uniform: sparse gather only when spikes present
      unsigned long long mm;
      mm = w0; while (mm) { int l = __builtin_ctzll(mm); mm &= mm - 1; acc += lwT[(size_t)(l) * D_ + e]; }
      mm = w1; while (mm) { int l = __builtin_ctzll(mm); mm &= mm - 1; acc += lwT[(size_t)(64 + l) * D_ + e]; }
      mm = w2; while (mm) { int l = __builtin_ctzll(mm); mm &= mm - 1; acc += lwT[(size_t)(128 + l) * D_ + e]; }
      mm = w3; while (mm) { int l = __builtin_ctzll(mm); mm &= mm - 1; acc += lwT[(size_t)(192 + l) * D_ + e]; }
    }
    float u = acc * sc + sh;          // BN2 (eval)
    v = 0.5f * (v + u);
    bool s = (v >= 1.0f);
    if (t >= t0) {
      unsigned long long myw = sb[idx + eq];
      float s1 = (float)((myw >> threadIdx.x) & 1ull);   // residual spike
      op[(size_t)t * ts] = (s ? 1.0f : 0.0f) + s1;
    }
    v = s ? 0.f : v;
  }
}

extern "C" void kernel_launch(void* const* d_in, const int* in_sizes, int n_in,
                              void* d_out, int out_size, void* d_ws, size_t ws_size,
                              hipStream_t stream) {
  const float* x    = (const float*)d_in[0];
  const float* pw_w = (const float*)d_in[1];
  const float* pw_b = (const float*)d_in[2];
  const float* dw_w = (const float*)d_in[3];
  const float* g1   = (const float*)d_in[4];
  const float* b1   = (const float*)d_in[5];
  const float* m1   = (const float*)d_in[6];
  const float* v1   = (const float*)d_in[7];
  const float* lw   = (const float*)d_in[8];
  const float* g2   = (const float*)d_in[9];
  const float* b2   = (const float*)d_in[10];
  const float* m2   = (const float*)d_in[11];
  const float* v2   = (const float*)d_in[12];
  float* out = (float*)d_out;

  char* ws = (char*)d_ws;
  __hip_bfloat16* h = (__hip_bfloat16*)ws;                              // 32,768,000 B
  unsigned long long* bits = (unsigned long long*)(ws + 32768000);      //  2,048,000 B
  float* lwT = (float*)(ws + 32768000 + 2048000);                       //    262,144 B

  k0_transpose<<<(D_ * D_) / 256, 256, 0, stream>>>(lw, lwT);
  dim3 g_gemm((B_ * T_) / 64, D_ / 64);
  k1_pw_gemm<<<g_gemm, 256, 0, stream>>>(x, pw_w, pw_b, h);
  dim3 g_k2(B_ * 4, NC_);
  k2_dw_lif<<<g_k2, 64, 0, stream>>>(h, dw_w, g1, b1, m1, v1, bits);
  dim3 g_k3(B_ * 4, NC_);
  k3_lin_lif<<<g_k3, 64, 0, stream>>>(bits, lwT, g2, b2, m2, v2, out);
}

// Round 3
// 202.731 us; speedup vs baseline: 3.0986x; 1.1527x over previous
//
#include <hip/hip_runtime.h>
#include <hip/hip_bf16.h>

#define B_  64
#define T_  1000
#define F_  140
#define D_  256
#define EPS_ 1e-5f

// time-chunked scan parameters: v-influence decays 2^-step (tau=2), so W=24
// warmup steps from v=0 reproduce the true state to <6e-8 before any chunk.
#define CL_ 25     // steps written per chunk
#define NC_ 40     // chunks (CL_*NC_ == T_)
#define W_  24     // warmup steps

typedef __attribute__((ext_vector_type(8))) short bf16x8;
typedef __attribute__((ext_vector_type(4))) float f32x4;

static __device__ inline short f2bf(float f) {
  __hip_bfloat16 h = __float2bfloat16(f);
  return *reinterpret_cast<short*>(&h);
}

// ---------------- K0: transpose lin_w (D,D) -> lwT (d-major) for coalesced gathers
__global__ __launch_bounds__(256) void k0_transpose(const float* __restrict__ lw,
                                                    float* __restrict__ lwT) {
  int i = blockIdx.x * 256 + threadIdx.x;   // i over D*D
  int e = i >> 8, d = i & 255;
  lwT[(size_t)d * D_ + e] = lw[(size_t)e * D_ + d];
}

// ---------------- K1: pointwise GEMM via bf16 MFMA.
// h[t,b,d] = sum_f x[b,t,f]*pw_w[d,f] + pw_b[d], output bf16 in (T,B,D).
// 128x128 tile, 4 waves, 4x4 mfma_16x16x32 per wave, K padded 140->160 (5 chunks
// of 32), double-buffered LDS staging with fused fp32->bf16 convert.
#define KP_ 40    // LDS row stride per chunk: 32 k + 8 pad (bank spread, 16B align)
__global__ __launch_bounds__(256) void k1_mfma(const float* __restrict__ x,
                                               const float* __restrict__ w,
                                               const float* __restrict__ bias,
                                               __hip_bfloat16* __restrict__ h) {
  __shared__ short smem[2 * 128 * KP_ * 2];          // As(2 bufs) + Bs(2 bufs) = 40 KB
  short* As = smem;                                   // [buf][row][KP_]
  short* Bs = smem + 2 * 128 * KP_;
  const int m0 = blockIdx.x * 128;                    // over M = B*T
  const int n0 = blockIdx.y * 128;                    // over D
  const int tid = threadIdx.x;
  const int lane = tid & 63, wv = tid >> 6;
  const int lr = lane & 15, quad = lane >> 4;
  const int mr = (wv & 1) * 64, nc = (wv >> 1) * 64;  // wave's 64x64 quadrant

  const int srow = tid >> 1;                          // staging: 2 threads/row
  const int sc4 = (tid & 1) * 4;                      // each stages 4 float4 (16 k)

  // stage chunk kc into buffer buf
  auto stage = [&](int kc, int buf) {
#pragma unroll
    for (int c = 0; c < 4; c++) {
      int c4 = sc4 + c;                               // 0..7 -> k offset c4*4 in chunk
      int kg = kc + c4 * 4;
      float4 av = make_float4(0.f, 0.f, 0.f, 0.f);
      float4 bv = make_float4(0.f, 0.f, 0.f, 0.f);
      if (kg < F_) {                                  // F=140, multiples of 4 -> full vec
        av = *(const float4*)(x + (size_t)(m0 + srow) * F_ + kg);
        bv = *(const float4*)(w + (size_t)(n0 + srow) * F_ + kg);
      }
      short* ap = As + buf * 128 * KP_ + srow * KP_ + c4 * 4;
      short* bp = Bs + buf * 128 * KP_ + srow * KP_ + c4 * 4;
      ap[0] = f2bf(av.x); ap[1] = f2bf(av.y); ap[2] = f2bf(av.z); ap[3] = f2bf(av.w);
      bp[0] = f2bf(bv.x); bp[1] = f2bf(bv.y); bp[2] = f2bf(bv.z); bp[3] = f2bf(bv.w);
    }
  };

  f32x4 acc[4][4] = {};
  stage(0, 0);
  __syncthreads();
#pragma unroll
  for (int kk = 0; kk < 5; kk++) {
    const int cur = kk & 1;
    if (kk < 4) stage((kk + 1) * 32, cur ^ 1);        // prefetch next chunk
    const short* ab = As + cur * 128 * KP_ + quad * 8;
    const short* bb = Bs + cur * 128 * KP_ + quad * 8;
    bf16x8 a[4], b[4];
#pragma unroll
    for (int i = 0; i < 4; i++) a[i] = *(const bf16x8*)(ab + (mr + i * 16 + lr) * KP_);
#pragma unroll
    for (int j = 0; j < 4; j++) b[j] = *(const bf16x8*)(bb + (nc + j * 16 + lr) * KP_);
#pragma unroll
    for (int i = 0; i < 4; i++)
#pragma unroll
      for (int j = 0; j < 4; j++)
        acc[i][j] = __builtin_amdgcn_mfma_f32_16x16x32_bf16(a[i], b[j], acc[i][j], 0, 0, 0);
    __syncthreads();
  }

  // epilogue: bias + bf16, bounce via LDS (reuse smem) for coalesced global stores
  short* Cs = smem;                                   // 128 x 136 (16B-aligned rows)
#pragma unroll
  for (int j = 0; j < 4; j++) {
    const int n = nc + j * 16 + lr;
    const float badd = bias[n0 + n];
#pragma unroll
    for (int i = 0; i < 4; i++) {
      const int mrow = mr + i * 16 + quad * 4;
#pragma unroll
      for (int r = 0; r < 4; r++)
        Cs[(mrow + r) * 136 + n] = f2bf(acc[i][j][r] + badd);
    }
  }
  __syncthreads();
  const int row = tid >> 1, half = tid & 1;
  const int m = m0 + row;
  const int bb2 = m / T_;
  const int t = m - bb2 * T_;
  __hip_bfloat16* dst = h + ((size_t)t * B_ + bb2) * D_ + n0 + half * 64;
  const short* src = Cs + row * 136 + half * 64;
#pragma unroll
  for (int c = 0; c < 4; c++)
    *(int4*)(dst + c * 8) = *(const int4*)(src + c * 8);
}

// ---------------- K2: depthwise conv (K=7, same pad) + BN1 + LIF1, time-chunked
// grid.x = b*4+dq (256), grid.y = time chunk (NC_). One thread per (b,d).
__global__ void k2_dw_lif(const __hip_bfloat16* __restrict__ h,
                          const float* __restrict__ dww,
                          const float* __restrict__ g1,
                          const float* __restrict__ b1,
                          const float* __restrict__ m1,
                          const float* __restrict__ v1,
                          unsigned long long* __restrict__ bits) {
  const int b = blockIdx.x >> 2;
  const int dq = blockIdx.x & 3;
  const int d = dq * 64 + threadIdx.x;
  const int t0 = blockIdx.y * CL_;
  const int tstart = (t0 - W_ > 0) ? t0 - W_ : 0;
  const int tend = t0 + CL_;          // <= T_
  const int nsteps = tend - tstart;   // <= CL_ + W_ = 49

  float w[7];
#pragma unroll
  for (int k = 0; k < 7; k++) w[k] = dww[d * 7 + k];
  const float sc = g1[d] * rsqrtf(v1[d] + EPS_);
  const float sh = b1[d] - m1[d] * sc;
  const __hip_bfloat16* hp = h + (size_t)b * D_ + d;
  const size_t ts = (size_t)B_ * D_;     // t-stride in h

  float win0 = (tstart - 3 >= 0) ? __bfloat162float(hp[(size_t)(tstart - 3) * ts]) : 0.f;
  float win1 = (tstart - 2 >= 0) ? __bfloat162float(hp[(size_t)(tstart - 2) * ts]) : 0.f;
  float win2 = (tstart - 1 >= 0) ? __bfloat162float(hp[(size_t)(tstart - 1) * ts]) : 0.f;
  float win3 = __bfloat162float(hp[(size_t)(tstart + 0) * ts]);
  float win4 = __bfloat162float(hp[(size_t)(tstart + 1) * ts]);
  float win5 = __bfloat162float(hp[(size_t)(tstart + 2) * ts]);
  float v = 0.f;

  const int U = 8;     // prefetch queue depth (small: no VGPR spill)
  float buf[U], nbuf[U];
#pragma unroll
  for (int i = 0; i < U; i++) {   // buf[i] = h[tstart+3+i]
    int tt = tstart + 3 + i;
    buf[i] = (tt < T_) ? __bfloat162float(hp[(size_t)tt * ts]) : 0.f;
  }
  for (int s0 = 0; s0 < nsteps; s0 += U) {
#pragma unroll
    for (int i = 0; i < U; i++) {   // prefetch next sub-chunk
      int tt = tstart + 3 + s0 + U + i;
      nbuf[i] = (tt < T_) ? __bfloat162float(hp[(size_t)tt * ts]) : 0.f;
    }
#pragma unroll
    for (int i = 0; i < U; i++) {
      if (s0 + i >= nsteps) break;         // wave-uniform
      const int t = tstart + s0 + i;
      float conv = win0 * w[0] + win1 * w[1] + win2 * w[2] + win3 * w[3] +
                   win4 * w[4] + win5 * w[5] + buf[i] * w[6];
      float u = conv * sc + sh;
      v = 0.5f * (v + u);                  // v += (u - v)/tau, tau = 2
      bool s = (v >= 1.0f);                // spike(v - V_TH)
      unsigned long long mask = __ballot(s);
      if (t >= t0 && threadIdx.x == 0)
        bits[((size_t)b * T_ + t) * 4 + dq] = mask;
      v = s ? 0.f : v;                     // hard reset
      win0 = win1; win1 = win2; win2 = win3; win3 = win4; win4 = win5; win5 = buf[i];
    }
#pragma unroll
    for (int i = 0; i < U; i++) buf[i] = nbuf[i];
  }
}

// ---------------- K3: sparse linear (spikes @ lin_w^T) + BN2 + LIF2 + residual
// grid.x = b*4+eq (256), grid.y = time chunk. Window bitmasks staged in LDS.
__global__ void k3_lin_lif(const unsigned long long* __restrict__ bits,
                           const float* __restrict__ lwT,
                           const float* __restrict__ g2,
                           const float* __restrict__ b2,
                           const float* __restrict__ m2,
                           const float* __restrict__ v2,
                           float* __restrict__ out) {
  __shared__ unsigned long long sb[(CL_ + W_) * 4];
  const int b = blockIdx.x >> 2;
  const int eq = blockIdx.x & 3;
  const int e = eq * 64 + threadIdx.x;
  const int t0 = blockIdx.y * CL_;
  const int tstart = (t0 - W_ > 0) ? t0 - W_ : 0;
  const int tend = t0 + CL_;
  const int nw = (tend - tstart) * 4;
  const unsigned long long* bp = bits + ((size_t)b * T_ + tstart) * 4;
  for (int i = threadIdx.x; i < nw; i += 64) sb[i] = bp[i];
  __syncthreads();

  const float sc = g2[e] * rsqrtf(v2[e] + EPS_);
  const float sh = b2[e] - m2[e] * sc;
  float v = 0.f;
  float* op = out + (size_t)b * D_ + e;
  const size_t ts = (size_t)B_ * D_;

  for (int t = tstart; t < tend; t++) {
    const int idx = (t - tstart) * 4;
    unsigned long long w0 = sb[idx + 0], w1 = sb[idx + 1];
    unsigned long long w2 = sb[idx + 2], w3 = sb[idx + 3];
    float acc = 0.f;
    if (w0 | w1 | w2 | w3) {   // wave-uniform: sparse gather only when spikes present
      unsigned long long mm;
      mm = w0; while (mm) { int l = __builtin_ctzll(mm); mm &= mm - 1; acc += lwT[(size_t)(l) * D_ + e]; }
      mm = w1; while (mm) { int l = __builtin_ctzll(mm); mm &= mm - 1; acc += lwT[(size_t)(64 + l) * D_ + e]; }
      mm = w2; while (mm) { int l = __builtin_ctzll(mm); mm &= mm - 1; acc += lwT[(size_t)(128 + l) * D_ + e]; }
      mm = w3; while (mm) { int l = __builtin_ctzll(mm); mm &= mm - 1; acc += lwT[(size_t)(192 + l) * D_ + e]; }
    }
    float u = acc * sc + sh;          // BN2 (eval)
    v = 0.5f * (v + u);
    bool s = (v >= 1.0f);
    if (t >= t0) {
      unsigned long long myw = sb[idx + eq];
      float s1 = (float)((myw >> threadIdx.x) & 1ull);   // residual spike
      op[(size_t)t * ts] = (s ? 1.0f : 0.0f) + s1;
    }
    v = s ? 0.f : v;
  }
}

extern "C" void kernel_launch(void* const* d_in, const int* in_sizes, int n_in,
                              void* d_out, int out_size, void* d_ws, size_t ws_size,
                              hipStream_t stream) {
  const float* x    = (const float*)d_in[0];
  const float* pw_w = (const float*)d_in[1];
  const float* pw_b = (const float*)d_in[2];
  const float* dw_w = (const float*)d_in[3];
  const float* g1   = (const float*)d_in[4];
  const float* b1   = (const float*)d_in[5];
  const float* m1   = (const float*)d_in[6];
  const float* v1   = (const float*)d_in[7];
  const float* lw   = (const float*)d_in[8];
  const float* g2   = (const float*)d_in[9];
  const float* b2   = (const float*)d_in[10];
  const float* m2   = (const float*)d_in[11];
  const float* v2   = (const float*)d_in[12];
  float* out = (float*)d_out;

  char* ws = (char*)d_ws;
  __hip_bfloat16* h = (__hip_bfloat16*)ws;                              // 32,768,000 B
  unsigned long long* bits = (unsigned long long*)(ws + 32768000);      //  2,048,000 B
  float* lwT = (float*)(ws + 32768000 + 2048000);                       //    262,144 B

  k0_transpose<<<(D_ * D_) / 256, 256, 0, stream>>>(lw, lwT);
  dim3 g_gemm((B_ * T_) / 128, D_ / 128);
  k1_mfma<<<g_gemm, 256, 0, stream>>>(x, pw_w, pw_b, h);
  dim3 g_k2(B_ * 4, NC_);
  k2_dw_lif<<<g_k2, 64, 0, stream>>>(h, dw_w, g1, b1, m1, v1, bits);
  dim3 g_k3(B_ * 4, NC_);
  k3_lin_lif<<<g_k3, 64, 0, stream>>>(bits, lwT, g2, b2, m2, v2, out);
}

// Round 4
// 177.710 us; speedup vs baseline: 3.5348x; 1.1408x over previous
//
#include <hip/hip_runtime.h>
#include <hip/hip_bf16.h>

#define B_  64
#define T_  1000
#define F_  140
#define D_  256
#define EPS_ 1e-5f

// time-chunked scan: v-influence decays 2^-step (tau=2); W=24 warmup steps from
// v=0 reproduce the true state to <6e-8 before any written step.
#define CL_ 50     // steps written per chunk
#define NC_ 20     // chunks (CL_*NC_ == T_)
#define W_  24     // warmup steps
#define ROWS_ (CL_ + W_ + 6)   // 80 LDS rows for k2 window

typedef __attribute__((ext_vector_type(8))) short bf16x8;
typedef __attribute__((ext_vector_type(4))) float f32x4;

static __device__ inline short f2bf(float f) {
  __hip_bfloat16 h = __float2bfloat16(f);
  return *reinterpret_cast<short*>(&h);
}
static __device__ inline float bf2f(short s) {
  unsigned int u = ((unsigned int)(unsigned short)s) << 16;
  return __uint_as_float(u);
}

// ---------------- K0: transpose lin_w (D,D) -> lwT (d-major) for coalesced gathers
__global__ __launch_bounds__(256) void k0_transpose(const float* __restrict__ lw,
                                                    float* __restrict__ lwT) {
  int i = blockIdx.x * 256 + threadIdx.x;
  int e = i >> 8, d = i & 255;
  lwT[(size_t)d * D_ + e] = lw[(size_t)e * D_ + d];
}

// ---------------- K1: pointwise GEMM via bf16 MFMA (unchanged from R2)
#define KP_ 40
__global__ __launch_bounds__(256) void k1_mfma(const float* __restrict__ x,
                                               const float* __restrict__ w,
                                               const float* __restrict__ bias,
                                               __hip_bfloat16* __restrict__ h) {
  __shared__ short smem[2 * 128 * KP_ * 2];
  short* As = smem;
  short* Bs = smem + 2 * 128 * KP_;
  const int m0 = blockIdx.x * 128;
  const int n0 = blockIdx.y * 128;
  const int tid = threadIdx.x;
  const int lane = tid & 63, wv = tid >> 6;
  const int lr = lane & 15, quad = lane >> 4;
  const int mr = (wv & 1) * 64, nc = (wv >> 1) * 64;

  const int srow = tid >> 1;
  const int sc4 = (tid & 1) * 4;

  auto stage = [&](int kc, int buf) {
#pragma unroll
    for (int c = 0; c < 4; c++) {
      int c4 = sc4 + c;
      int kg = kc + c4 * 4;
      float4 av = make_float4(0.f, 0.f, 0.f, 0.f);
      float4 bv = make_float4(0.f, 0.f, 0.f, 0.f);
      if (kg < F_) {
        av = *(const float4*)(x + (size_t)(m0 + srow) * F_ + kg);
        bv = *(const float4*)(w + (size_t)(n0 + srow) * F_ + kg);
      }
      short* ap = As + buf * 128 * KP_ + srow * KP_ + c4 * 4;
      short* bp = Bs + buf * 128 * KP_ + srow * KP_ + c4 * 4;
      ap[0] = f2bf(av.x); ap[1] = f2bf(av.y); ap[2] = f2bf(av.z); ap[3] = f2bf(av.w);
      bp[0] = f2bf(bv.x); bp[1] = f2bf(bv.y); bp[2] = f2bf(bv.z); bp[3] = f2bf(bv.w);
    }
  };

  f32x4 acc[4][4] = {};
  stage(0, 0);
  __syncthreads();
#pragma unroll
  for (int kk = 0; kk < 5; kk++) {
    const int cur = kk & 1;
    if (kk < 4) stage((kk + 1) * 32, cur ^ 1);
    const short* ab = As + cur * 128 * KP_ + quad * 8;
    const short* bb = Bs + cur * 128 * KP_ + quad * 8;
    bf16x8 a[4], b[4];
#pragma unroll
    for (int i = 0; i < 4; i++) a[i] = *(const bf16x8*)(ab + (mr + i * 16 + lr) * KP_);
#pragma unroll
    for (int j = 0; j < 4; j++) b[j] = *(const bf16x8*)(bb + (nc + j * 16 + lr) * KP_);
#pragma unroll
    for (int i = 0; i < 4; i++)
#pragma unroll
      for (int j = 0; j < 4; j++)
        acc[i][j] = __builtin_amdgcn_mfma_f32_16x16x32_bf16(a[i], b[j], acc[i][j], 0, 0, 0);
    __syncthreads();
  }

  short* Cs = smem;
#pragma unroll
  for (int j = 0; j < 4; j++) {
    const int n = nc + j * 16 + lr;
    const float badd = bias[n0 + n];
#pragma unroll
    for (int i = 0; i < 4; i++) {
      const int mrow = mr + i * 16 + quad * 4;
#pragma unroll
      for (int r = 0; r < 4; r++)
        Cs[(mrow + r) * 136 + n] = f2bf(acc[i][j][r] + badd);
    }
  }
  __syncthreads();
  const int row = tid >> 1, half = tid & 1;
  const int m = m0 + row;
  const int bb2 = m / T_;
  const int t = m - bb2 * T_;
  __hip_bfloat16* dst = h + ((size_t)t * B_ + bb2) * D_ + n0 + half * 64;
  const short* src = Cs + row * 136 + half * 64;
#pragma unroll
  for (int c = 0; c < 4; c++)
    *(int4*)(dst + c * 8) = *(const int4*)(src + c * 8);
}

// ---------------- K2: depthwise conv (K=7) + BN1 + LIF1, LDS-staged scan
// grid = (b, chunk), 256 threads = all d. Window staged in LDS with bf16x8 loads.
__global__ __launch_bounds__(256) void k2_dw_lif(const __hip_bfloat16* __restrict__ h,
                                                 const float* __restrict__ dww,
                                                 const float* __restrict__ g1,
                                                 const float* __restrict__ b1,
                                                 const float* __restrict__ m1,
                                                 const float* __restrict__ v1,
                                                 unsigned long long* __restrict__ bits) {
  __shared__ short hs[ROWS_ * D_];          // 40,960 B -> 4 blocks/CU
  const int b = blockIdx.x;
  const int t0 = blockIdx.y * CL_;
  const int tstart = (t0 >= W_) ? t0 - W_ : 0;
  const int nwarm = t0 - tstart;            // 0 (chunk 0) or 24
  const int nrows = nwarm + CL_ + 6;
  const int tid = threadIdx.x;

  {  // stage rows t = tstart-3 .. t0+CL_+2 (zero-padded outside [0,T))
    const int c8 = (tid & 31) * 8;
    for (int r = tid >> 5; r < nrows; r += 8) {
      const int t = tstart - 3 + r;
      bf16x8 val = {0, 0, 0, 0, 0, 0, 0, 0};
      if (t >= 0 && t < T_)
        val = *(const bf16x8*)((const short*)h + ((size_t)t * B_ + b) * D_ + c8);
      *(bf16x8*)(hs + r * D_ + c8) = val;
    }
  }
  __syncthreads();

  const int d = tid;
  float w[7];
#pragma unroll
  for (int k = 0; k < 7; k++) w[k] = dww[d * 7 + k];
  const float sc = g1[d] * rsqrtf(v1[d] + EPS_);
  const float shf = b1[d] - m1[d] * sc;

  float win0 = bf2f(hs[0 * D_ + d]);
  float win1 = bf2f(hs[1 * D_ + d]);
  float win2 = bf2f(hs[2 * D_ + d]);
  float win3 = bf2f(hs[3 * D_ + d]);
  float win4 = bf2f(hs[4 * D_ + d]);
  float win5 = bf2f(hs[5 * D_ + d]);
  float v = 0.f;
  int s = 0;
  for (; s < nwarm; s++) {                  // warmup: no ballot, no store
    float tap6 = bf2f(hs[(s + 6) * D_ + d]);
    float conv = win0 * w[0] + win1 * w[1] + win2 * w[2] + win3 * w[3] +
                 win4 * w[4] + win5 * w[5] + tap6 * w[6];
    float u = conv * sc + shf;
    v = 0.5f * (v + u);
    v = (v >= 1.0f) ? 0.f : v;
    win0 = win1; win1 = win2; win2 = win3; win3 = win4; win4 = win5; win5 = tap6;
  }
  unsigned long long* bp = bits + ((size_t)b * T_ + t0) * 4 + (tid >> 6);
  const bool lane0 = (tid & 63) == 0;
#pragma unroll 5
  for (int i = 0; i < CL_; i++, s++) {
    float tap6 = bf2f(hs[(s + 6) * D_ + d]);
    float conv = win0 * w[0] + win1 * w[1] + win2 * w[2] + win3 * w[3] +
                 win4 * w[4] + win5 * w[5] + tap6 * w[6];
    float u = conv * sc + shf;
    v = 0.5f * (v + u);
    bool sp = (v >= 1.0f);
    unsigned long long mask = __ballot(sp);
    if (lane0) bp[(size_t)i * 4] = mask;
    v = sp ? 0.f : v;
    win0 = win1; win1 = win2; win2 = win3; win3 = win4; win4 = win5; win5 = tap6;
  }
}

// ---------------- K3: sparse linear (spikes @ lin_w^T) + BN2 + LIF2 + residual
// grid = (b, chunk), 256 threads = all e. Bitmasks in LDS (uniform broadcast reads).
__global__ __launch_bounds__(256) void k3_lin_lif(const unsigned long long* __restrict__ bits,
                                                  const float* __restrict__ lwT,
                                                  const float* __restrict__ g2,
                                                  const float* __restrict__ b2,
                                                  const float* __restrict__ m2,
                                                  const float* __restrict__ v2,
                                                  float* __restrict__ out) {
  __shared__ unsigned long long sb[(CL_ + W_) * 4];
  const int b = blockIdx.x;
  const int t0 = blockIdx.y * CL_;
  const int tstart = (t0 >= W_) ? t0 - W_ : 0;
  const int nwarm = t0 - tstart;
  const int nsteps = nwarm + CL_;
  const int e = threadIdx.x;
  const unsigned long long* gbp = bits + ((size_t)b * T_ + tstart) * 4;
  for (int i = e; i < nsteps * 4; i += 256) sb[i] = gbp[i];
  __syncthreads();

  const float sc = g2[e] * rsqrtf(v2[e] + EPS_);
  const float shf = b2[e] - m2[e] * sc;
  const int eq = e >> 6, eb = e & 63;
  float v = 0.f;
  int s = 0;
  for (; s < nwarm; s++) {                  // warmup: no store
    unsigned long long w0 = sb[s * 4 + 0], w1 = sb[s * 4 + 1];
    unsigned long long w2 = sb[s * 4 + 2], w3 = sb[s * 4 + 3];
    float acc = 0.f;
    if (w0 | w1 | w2 | w3) {
      unsigned long long mm;
      mm = w0; while (mm) { int l = __builtin_ctzll(mm); mm &= mm - 1; acc += lwT[(size_t)(l) * D_ + e]; }
      mm = w1; while (mm) { int l = __builtin_ctzll(mm); mm &= mm - 1; acc += lwT[(size_t)(64 + l) * D_ + e]; }
      mm = w2; while (mm) { int l = __builtin_ctzll(mm); mm &= mm - 1; acc += lwT[(size_t)(128 + l) * D_ + e]; }
      mm = w3; while (mm) { int l = __builtin_ctzll(mm); mm &= mm - 1; acc += lwT[(size_t)(192 + l) * D_ + e]; }
    }
    float u = acc * sc + shf;
    v = 0.5f * (v + u);
    v = (v >= 1.0f) ? 0.f : v;
  }
  float* op = out + ((size_t)t0 * B_ + b) * D_ + e;
  const size_t ts = (size_t)B_ * D_;
#pragma unroll 5
  for (int i = 0; i < CL_; i++, s++) {
    unsigned long long w0 = sb[s * 4 + 0], w1 = sb[s * 4 + 1];
    unsigned long long w2 = sb[s * 4 + 2], w3 = sb[s * 4 + 3];
    float acc = 0.f;
    if (w0 | w1 | w2 | w3) {
      unsigned long long mm;
      mm = w0; while (mm) { int l = __builtin_ctzll(mm); mm &= mm - 1; acc += lwT[(size_t)(l) * D_ + e]; }
      mm = w1; while (mm) { int l = __builtin_ctzll(mm); mm &= mm - 1; acc += lwT[(size_t)(64 + l) * D_ + e]; }
      mm = w2; while (mm) { int l = __builtin_ctzll(mm); mm &= mm - 1; acc += lwT[(size_t)(128 + l) * D_ + e]; }
      mm = w3; while (mm) { int l = __builtin_ctzll(mm); mm &= mm - 1; acc += lwT[(size_t)(192 + l) * D_ + e]; }
    }
    float u = acc * sc + shf;
    v = 0.5f * (v + u);
    bool sp = (v >= 1.0f);
    unsigned long long myw = sb[s * 4 + eq];
    float s1 = (float)((myw >> eb) & 1ull);
    op[(size_t)i * ts] = (sp ? 1.0f : 0.0f) + s1;
    v = sp ? 0.f : v;
  }
}

extern "C" void kernel_launch(void* const* d_in, const int* in_sizes, int n_in,
                              void* d_out, int out_size, void* d_ws, size_t ws_size,
                              hipStream_t stream) {
  const float* x    = (const float*)d_in[0];
  const float* pw_w = (const float*)d_in[1];
  const float* pw_b = (const float*)d_in[2];
  const float* dw_w = (const float*)d_in[3];
  const float* g1   = (const float*)d_in[4];
  const float* b1   = (const float*)d_in[5];
  const float* m1   = (const float*)d_in[6];
  const float* v1   = (const float*)d_in[7];
  const float* lw   = (const float*)d_in[8];
  const float* g2   = (const float*)d_in[9];
  const float* b2   = (const float*)d_in[10];
  const float* m2   = (const float*)d_in[11];
  const float* v2   = (const float*)d_in[12];
  float* out = (float*)d_out;

  char* ws = (char*)d_ws;
  __hip_bfloat16* h = (__hip_bfloat16*)ws;                              // 32,768,000 B
  unsigned long long* bits = (unsigned long long*)(ws + 32768000);      //  2,048,000 B
  float* lwT = (float*)(ws + 32768000 + 2048000);                       //    262,144 B

  k0_transpose<<<(D_ * D_) / 256, 256, 0, stream>>>(lw, lwT);
  dim3 g_gemm((B_ * T_) / 128, D_ / 128);
  k1_mfma<<<g_gemm, 256, 0, stream>>>(x, pw_w, pw_b, h);
  dim3 g_scan(B_, NC_);
  k2_dw_lif<<<g_scan, 256, 0, stream>>>(h, dw_w, g1, b1, m1, v1, bits);
  k3_lin_lif<<<g_scan, 256, 0, stream>>>(bits, lwT, g2, b2, m2, v2, out);
}

// Round 5
// 169.161 us; speedup vs baseline: 3.7135x; 1.0505x over previous
//
#include <hip/hip_runtime.h>
#include <hip/hip_bf16.h>

#define B_  64
#define T_  1000
#define F_  140
#define D_  256
#define EPS_ 1e-5f

// k3 time-chunking (unchanged): tau=2 => v-influence decays 2^-step; W=24 warmup
// steps from v=0 reproduce the true LIF state to <6e-8 before any written step.
#define CL_ 50
#define NC_ 20
#define W_  24

// fused k12 chunking: GEMM tile = 128 t-rows; hbuf rows = h[a-3 .. a+124].
// mid chunks: warmup lt 3..26 (24 steps), write lt 27..121 (95 steps).
#define CW_  95     // write steps per mid chunk
#define NCH_ 11     // chunks: 122 + 10*95 = 1072 >= 1000

typedef __attribute__((ext_vector_type(8))) short bf16x8;
typedef __attribute__((ext_vector_type(4))) short bf16x4;
typedef __attribute__((ext_vector_type(4))) float f32x4;

static __device__ inline short f2bf(float f) {
  __hip_bfloat16 h = __float2bfloat16(f);
  return *reinterpret_cast<short*>(&h);
}
static __device__ inline float bf2f(short s) {
  unsigned int u = ((unsigned int)(unsigned short)s) << 16;
  return __uint_as_float(u);
}

// ---------------- K0: lwT transpose + pw_w -> bf16 padded [256][160]
__global__ __launch_bounds__(256) void k0_prep(const float* __restrict__ lw,
                                               float* __restrict__ lwT,
                                               const float* __restrict__ pw,
                                               short* __restrict__ wbf) {
  int i = blockIdx.x * 256 + threadIdx.x;
  if (i < 65536) {
    int e = i >> 8, d = i & 255;
    lwT[(size_t)d * D_ + e] = lw[(size_t)e * D_ + d];
  } else if (i < 65536 + 256 * 160) {
    int j = i - 65536;
    int n = j / 160, k = j - n * 160;
    wbf[j] = (k < F_) ? f2bf(pw[(size_t)n * F_ + k]) : (short)0;
  }
}

// ---------------- K12: fused pointwise-GEMM + depthwise conv + BN1 + LIF1 -> bits
// grid = (b, chunk). 256 threads, 4 waves. GEMM: M=128 t-rows, N=256, K=160(pad),
// bf16 MFMA 16x16x32, double-buffered LDS staging. C+bias -> LDS hbuf (128x256
// bf16, overlays staging), then in-LDS conv/scan, ballot -> bit masks.
__global__ __launch_bounds__(256, 2) void k12_fused(const float* __restrict__ x,
                                                    const short* __restrict__ wbf,
                                                    const float* __restrict__ bias,
                                                    const float* __restrict__ dww,
                                                    const float* __restrict__ g1,
                                                    const float* __restrict__ b1,
                                                    const float* __restrict__ m1,
                                                    const float* __restrict__ v1,
                                                    unsigned long long* __restrict__ bits) {
  __shared__ short smem[32768];            // 65,536 B (= static cap): As|Bs, then hbuf
  short* As = smem;                         // 2 x 128 x 40  (10240 shorts)
  short* Bs = smem + 10240;                 // 2 x 256 x 40  (20480 shorts)
  const int b = blockIdx.x;
  const int c = blockIdx.y;
  const int a = CW_ * c;                    // GEMM t-row base (c=0 -> 0)
  const int tid = threadIdx.x;
  const int lane = tid & 63, wv = tid >> 6;
  const int lr = lane & 15, quad = lane >> 4;
  const int mr = (wv & 1) * 64;             // wave quadrant: 64 m x 128 n
  const int nc0 = (wv >> 1) * 128;

  // staging: A 2 threads/row (4 float4 each), B 1 thread/row (4 bf16x8)
  const int srow = tid >> 1;
  const int sc4 = (tid & 1) * 4;
  const bool arow_ok = (a + srow) < T_;
  const float* xrow = x + ((size_t)b * T_ + a + srow) * F_;
  const short* wsrc0 = wbf + (size_t)tid * 160;

  auto stage = [&](int kc, int buf) {
    short* abase = As + buf * (128 * 40) + srow * 40;
#pragma unroll
    for (int s = 0; s < 4; s++) {
      int c4 = sc4 + s;
      int kg = kc + c4 * 4;
      float4 av = make_float4(0.f, 0.f, 0.f, 0.f);
      if (arow_ok && kg < F_) av = *(const float4*)(xrow + kg);
      bf16x4 pk = {f2bf(av.x), f2bf(av.y), f2bf(av.z), f2bf(av.w)};
      *(bf16x4*)(abase + c4 * 4) = pk;
    }
    short* bbase = Bs + buf * (256 * 40) + tid * 40;
    const short* wsrc = wsrc0 + kc;
#pragma unroll
    for (int s = 0; s < 4; s++)
      *(bf16x8*)(bbase + s * 8) = *(const bf16x8*)(wsrc + s * 8);
  };

  f32x4 acc[4][8] = {};
  stage(0, 0);
  __syncthreads();
#pragma unroll
  for (int kk = 0; kk < 5; kk++) {
    const int cur = kk & 1;
    if (kk < 4) stage((kk + 1) * 32, cur ^ 1);
    const short* ap = As + cur * (128 * 40) + quad * 8;
    const short* bp = Bs + cur * (256 * 40) + quad * 8;
    bf16x8 af[4], bfr[8];
#pragma unroll
    for (int i = 0; i < 4; i++) af[i] = *(const bf16x8*)(ap + (mr + i * 16 + lr) * 40);
#pragma unroll
    for (int j = 0; j < 8; j++) bfr[j] = *(const bf16x8*)(bp + (nc0 + j * 16 + lr) * 40);
#pragma unroll
    for (int i = 0; i < 4; i++)
#pragma unroll
      for (int j = 0; j < 8; j++)
        acc[i][j] = __builtin_amdgcn_mfma_f32_16x16x32_bf16(af[i], bfr[j], acc[i][j], 0, 0, 0);
    __syncthreads();
  }

  // ---- C + bias -> hbuf (bf16). hbuf[i] = h[a-3+i], i in [0,128). Rows t>=T -> 0.
  short* hbuf = smem;                       // 128 x 256, overlays As/Bs
  if (c == 0) {                             // rows t<0 are conv zero-pad
    hbuf[0 * D_ + tid] = 0; hbuf[1 * D_ + tid] = 0; hbuf[2 * D_ + tid] = 0;
  }
#pragma unroll
  for (int j = 0; j < 8; j++) {
    const int n = nc0 + j * 16 + lr;
    const float badd = bias[n];
#pragma unroll
    for (int i = 0; i < 4; i++) {
      const int m = mr + i * 16 + quad * 4;
#pragma unroll
      for (int r = 0; r < 4; r++) {
        const int mm = m + r;
        if (mm < 125) {                     // hbuf holds h[a .. a+124] at rows 3..127
          short val = ((a + mm) < T_) ? f2bf(acc[i][j][r] + badd) : (short)0;
          hbuf[(mm + 3) * D_ + n] = val;
        }
      }
    }
  }
  __syncthreads();

  // ---- depthwise conv (K=7) + BN1 + LIF1 scan, one thread per d
  const int d = tid;
  float w[7];
#pragma unroll
  for (int k = 0; k < 7; k++) w[k] = dww[d * 7 + k];
  const float sc = g1[d] * rsqrtf(v1[d] + EPS_);
  const float shf = b1[d] - m1[d] * sc;

  const int lt0 = (c == 0) ? 0 : 3;
  const int nwarm = (c == 0) ? 0 : W_;
  const int tw0 = a + ((c == 0) ? 0 : 27);  // first written t
  int nwrite = (c == 0) ? 122 : CW_;
  if (nwrite > T_ - tw0) nwrite = T_ - tw0; // last chunk clip

  float win0 = bf2f(hbuf[(lt0 + 0) * D_ + d]);
  float win1 = bf2f(hbuf[(lt0 + 1) * D_ + d]);
  float win2 = bf2f(hbuf[(lt0 + 2) * D_ + d]);
  float win3 = bf2f(hbuf[(lt0 + 3) * D_ + d]);
  float win4 = bf2f(hbuf[(lt0 + 4) * D_ + d]);
  float win5 = bf2f(hbuf[(lt0 + 5) * D_ + d]);
  float v = 0.f;
  int s = 0;
  for (; s < nwarm; s++) {                  // warmup: no ballot/store
    float tap6 = bf2f(hbuf[(lt0 + s + 6) * D_ + d]);
    float conv = win0 * w[0] + win1 * w[1] + win2 * w[2] + win3 * w[3] +
                 win4 * w[4] + win5 * w[5] + tap6 * w[6];
    float u = conv * sc + shf;
    v = 0.5f * (v + u);
    v = (v >= 1.0f) ? 0.f : v;
    win0 = win1; win1 = win2; win2 = win3; win3 = win4; win4 = win5; win5 = tap6;
  }
  unsigned long long* bp2 = bits + ((size_t)b * T_ + tw0) * 4 + wv;
  const bool lane0 = (lane == 0);
  for (int i2 = 0; i2 < nwrite; i2++, s++) {
    float tap6 = bf2f(hbuf[(lt0 + s + 6) * D_ + d]);
    float conv = win0 * w[0] + win1 * w[1] + win2 * w[2] + win3 * w[3] +
                 win4 * w[4] + win5 * w[5] + tap6 * w[6];
    float u = conv * sc + shf;
    v = 0.5f * (v + u);
    bool sp = (v >= 1.0f);
    unsigned long long mask = __ballot(sp);
    if (lane0) bp2[(size_t)i2 * 4] = mask;
    v = sp ? 0.f : v;
    win0 = win1; win1 = win2; win2 = win3; win3 = win4; win4 = win5; win5 = tap6;
  }
}

// ---------------- K3: sparse linear (spikes @ lin_w^T) + BN2 + LIF2 + residual
__global__ __launch_bounds__(256) void k3_lin_lif(const unsigned long long* __restrict__ bits,
                                                  const float* __restrict__ lwT,
                                                  const float* __restrict__ g2,
                                                  const float* __restrict__ b2,
                                                  const float* __restrict__ m2,
                                                  const float* __restrict__ v2,
                                                  float* __restrict__ out) {
  __shared__ unsigned long long sb[(CL_ + W_) * 4];
  const int b = blockIdx.x;
  const int t0 = blockIdx.y * CL_;
  const int tstart = (t0 >= W_) ? t0 - W_ : 0;
  const int nwarm = t0 - tstart;
  const int nsteps = nwarm + CL_;
  const int e = threadIdx.x;
  const unsigned long long* gbp = bits + ((size_t)b * T_ + tstart) * 4;
  for (int i = e; i < nsteps * 4; i += 256) sb[i] = gbp[i];
  __syncthreads();

  const float sc = g2[e] * rsqrtf(v2[e] + EPS_);
  const float shf = b2[e] - m2[e] * sc;
  const int eq = e >> 6, eb = e & 63;
  float v = 0.f;
  int s = 0;
  for (; s < nwarm; s++) {
    unsigned long long w0 = sb[s * 4 + 0], w1 = sb[s * 4 + 1];
    unsigned long long w2 = sb[s * 4 + 2], w3 = sb[s * 4 + 3];
    float acc = 0.f;
    if (w0 | w1 | w2 | w3) {
      unsigned long long mm;
      mm = w0; while (mm) { int l = __builtin_ctzll(mm); mm &= mm - 1; acc += lwT[(size_t)(l) * D_ + e]; }
      mm = w1; while (mm) { int l = __builtin_ctzll(mm); mm &= mm - 1; acc += lwT[(size_t)(64 + l) * D_ + e]; }
      mm = w2; while (mm) { int l = __builtin_ctzll(mm); mm &= mm - 1; acc += lwT[(size_t)(128 + l) * D_ + e]; }
      mm = w3; while (mm) { int l = __builtin_ctzll(mm); mm &= mm - 1; acc += lwT[(size_t)(192 + l) * D_ + e]; }
    }
    float u = acc * sc + shf;
    v = 0.5f * (v + u);
    v = (v >= 1.0f) ? 0.f : v;
  }
  float* op = out + ((size_t)t0 * B_ + b) * D_ + e;
  const size_t ts = (size_t)B_ * D_;
#pragma unroll 5
  for (int i = 0; i < CL_; i++, s++) {
    unsigned long long w0 = sb[s * 4 + 0], w1 = sb[s * 4 + 1];
    unsigned long long w2 = sb[s * 4 + 2], w3 = sb[s * 4 + 3];
    float acc = 0.f;
    if (w0 | w1 | w2 | w3) {
      unsigned long long mm;
      mm = w0; while (mm) { int l = __builtin_ctzll(mm); mm &= mm - 1; acc += lwT[(size_t)(l) * D_ + e]; }
      mm = w1; while (mm) { int l = __builtin_ctzll(mm); mm &= mm - 1; acc += lwT[(size_t)(64 + l) * D_ + e]; }
      mm = w2; while (mm) { int l = __builtin_ctzll(mm); mm &= mm - 1; acc += lwT[(size_t)(128 + l) * D_ + e]; }
      mm = w3; while (mm) { int l = __builtin_ctzll(mm); mm &= mm - 1; acc += lwT[(size_t)(192 + l) * D_ + e]; }
    }
    float u = acc * sc + shf;
    v = 0.5f * (v + u);
    bool sp = (v >= 1.0f);
    unsigned long long myw = sb[s * 4 + eq];
    float s1 = (float)((myw >> eb) & 1ull);
    op[(size_t)i * ts] = (sp ? 1.0f : 0.0f) + s1;
    v = sp ? 0.f : v;
  }
}

extern "C" void kernel_launch(void* const* d_in, const int* in_sizes, int n_in,
                              void* d_out, int out_size, void* d_ws, size_t ws_size,
                              hipStream_t stream) {
  const float* x    = (const float*)d_in[0];
  const float* pw_w = (const float*)d_in[1];
  const float* pw_b = (const float*)d_in[2];
  const float* dw_w = (const float*)d_in[3];
  const float* g1   = (const float*)d_in[4];
  const float* b1   = (const float*)d_in[5];
  const float* m1   = (const float*)d_in[6];
  const float* v1   = (const float*)d_in[7];
  const float* lw   = (const float*)d_in[8];
  const float* g2   = (const float*)d_in[9];
  const float* b2   = (const float*)d_in[10];
  const float* m2   = (const float*)d_in[11];
  const float* v2   = (const float*)d_in[12];
  float* out = (float*)d_out;

  char* ws = (char*)d_ws;
  unsigned long long* bits = (unsigned long long*)ws;      // 2,048,000 B
  float* lwT = (float*)(ws + 2048000);                     //   262,144 B
  short* wbf = (short*)(ws + 2048000 + 262144);            //    81,920 B

  k0_prep<<<(65536 + 256 * 160 + 255) / 256, 256, 0, stream>>>(lw, lwT, pw_w, wbf);
  dim3 g_k12(B_, NCH_);
  k12_fused<<<g_k12, 256, 0, stream>>>(x, wbf, pw_b, dw_w, g1, b1, m1, v1, bits);
  dim3 g_k3(B_, NC_);
  k3_lin_lif<<<g_k3, 256, 0, stream>>>(bits, lwT, g2, b2, m2, v2, out);
}